// Round 5
// baseline (1372.379 us; speedup 1.0000x reference)
//
#include <hip/hip_runtime.h>
#include <stdint.h>

// LSTM B=256,T=512,F=32,U=350; gates i,f,g(relu),o; h=o*relu(c); out=h.dw+db
//
// R12: zero-drain handoff + speculative verify.
//  R11 (4.4k cy/step): chain = gates(400) -> RELEASE drain(350) -> tag
//  visible(200) -> poll(250-400) -> data load(350) -> MFMA(450), plus the
//  dense-head shfl chain (300) serial in program order.
//  Changes:
//   - fast buffer back to R10's PROVEN tag-in-word u32 format+layout
//     (word=(bf16<<16)|tag16; lane L's frag = 16 contiguous B at
//     blk*1024+L*16). Producer: 4 fire-and-forget workgroup stores; tag
//     array store is now RELAXED (hint only) -> no vmcnt drain anywhere.
//   - consumer: tag pre-gate (cheap 250cy poll) -> load 44 u64 ->
//     SPECULATIVE MFMA: run the 44 MFMAs (C-in = saved kc0 acc0) while the
//     64-bit tag-check runs concurrently on the VALU pipe (free under the
//     MFMA issue). Verify-fail (tag-ahead-of-data race, rare) = reload +
//     redo from acc0. Correctness never rests on the tag hint.
//   - dense head for t-1 computed in the data-load flight shadow.
//   - distress/mirror protocol as R11 (mirror = same layout now; degraded
//     mode skips pre-gate and spins the same verify loop on the mirror;
//     verify-retry escalates to distress after 4096 tries when !mm).
//  Depth-2 ping-pong proof unchanged (reader-completion = verify-pass,
//  which postdates tag-pass; writer gating argument identical).

#define T_   512
#define F_   32
#define U_   350
#define G4   1400
#define NGRP 16
#define NB   16
#define NCB  11
#define KC   12
#define NT   88
#define SLOTW 5632      // u32 words per h slot (both buffers, R10 layout)

typedef __attribute__((ext_vector_type(8))) short  short8;
typedef __attribute__((ext_vector_type(4))) short  short4_;
typedef __attribute__((ext_vector_type(4))) float  float4_;
typedef unsigned long long u64t;

__device__ __forceinline__ short f2bf(float f) {
  union { float f; uint32_t u; } v; v.f = f;
  return (short)((v.u + 0x7FFFu + ((v.u >> 16) & 1u)) >> 16);
}

// ---- workspace layout (bytes) ----
#define SZ_W     (NT*KC*64*8*2u)                        // 1,081,344
#define OFF_XBF  (SZ_W)
#define SZ_XBF   (256u*T_*F_*2u)                        // 8,388,608
#define OFF_HBUF (OFF_XBF + SZ_XBF)
#define SZ_HBUF  (NGRP*2u*SLOTW*4u)                     // 720,896
#define OFF_HMIR (OFF_HBUF + SZ_HBUF)
#define SZ_HMIR  (NGRP*2u*SLOTW*4u)                     // 720,896
#define OFF_TAG  (OFF_HMIR + SZ_HMIR)
#define SZ_TAG   (NGRP*2u*32u*4u)                       // 4,096
#define OFF_FLG  (OFF_TAG + SZ_TAG)
#define SZ_FLG   (NGRP*16u*4u)                          // 1,024
#define OFF_WP   (OFF_FLG + SZ_FLG)
#define SZ_WP    (NGRP*NCB*NB*T_*4u)                    // 5,767,168

// ---- prep: W_swz[kc][tile][lane][8] bf16 in MFMA B-fragment order ----
__global__ void prep_w(const float* __restrict__ kern,
                       const float* __restrict__ rk,
                       const float* __restrict__ bias,
                       short* __restrict__ wswz) {
  const int tile = blockIdx.x, lane = threadIdx.x;
  const int g = tile / 22, jt = tile % 22;
  const int colg = jt * 16 + (lane & 15);
  const int src = g * U_ + colg;
  const bool valid = (colg < U_);
  const int kbase = (lane >> 4) * 8;
  for (int kc = 0; kc < KC; ++kc) {
    short8 pack;
    #pragma unroll
    for (int jj = 0; jj < 8; ++jj) {
      int k = kc * 32 + kbase + jj;
      float v = 0.f;
      if (valid) {
        if (k < F_)            v = kern[k * G4 + src];
        else if (k < F_ + U_)  v = rk[(k - F_) * G4 + src];
        else if (k == F_ + U_) v = bias[src];
      }
      pack[jj] = f2bf(v);
    }
    *(short8*)(wswz + (((size_t)kc * NT + tile) * 64 + lane) * 8) = pack;
  }
}

// ---- prep: x f32 -> bf16 ([b][t][f], contiguous 16B A-frag loads) ----
__global__ void prep_x(const float* __restrict__ x, short* __restrict__ xbf) {
  int i = (blockIdx.x * 256 + threadIdx.x) * 4;
  float4_ v = *(const float4_*)(x + i);
  short4_ o;
  #pragma unroll
  for (int jj = 0; jj < 4; ++jj) o[jj] = f2bf(v[jj]);
  *(short4_*)(xbf + i) = o;
}

// ---- init: slot1 = h_{-1}=0 with tag 0 (bias col 350 = bf16 1.0) ----
// Both buffers, same R10 layout. Slot 0 needs no init (tag-gated/poison-
// safe). Tag slots init 0: step-0 readers want 0 (pass), step-1 want 1.
__global__ void init_all(uint32_t* __restrict__ hbuf32,
                         uint32_t* __restrict__ hmir32,
                         uint32_t* __restrict__ tagbuf,
                         uint32_t* __restrict__ flagbuf) {
  int i = blockIdx.x * 256 + threadIdx.x;            // 0 .. NGRP*SLOTW-1
  int grp = i / SLOTW, rem = i % SLOTW;
  int blk = rem >> 8, off = rem & 255;
  int fi = blk >> 1, fk2 = blk & 1, fquadc = off >> 6;
  int fk1 = (off >> 1) & 1, fb = off & 1;
  int fcol = fi * 32 + fquadc * 8 + fk2 * 4 + fk1 * 2 + fb;
  uint32_t v = (fcol == 350) ? 0x3F800000u : 0u;
  size_t idx = (size_t)(grp * 2 + 1) * SLOTW + rem;
  hbuf32[idx] = v;
  hmir32[idx] = v;
  if (rem < 32) {
    tagbuf[(size_t)(grp * 2 + 0) * 32 + rem] = 0u;
    tagbuf[(size_t)(grp * 2 + 1) * 32 + rem] = 0u;
  }
  if (rem == 32) flagbuf[grp * 16] = 0u;
}

__device__ __forceinline__ void loadq44(u64t* q, const u64t* dq) {
  #pragma unroll
  for (int i = 0; i < 11; ++i) {
    const u64t* pa = dq + (size_t)(2 * i) * 128;
    const u64t* pb = dq + (size_t)(2 * i + 1) * 128;
    q[4 * i + 0] = __hip_atomic_load(pa,     __ATOMIC_RELAXED, __HIP_MEMORY_SCOPE_AGENT);
    q[4 * i + 1] = __hip_atomic_load(pa + 1, __ATOMIC_RELAXED, __HIP_MEMORY_SCOPE_AGENT);
    q[4 * i + 2] = __hip_atomic_load(pb,     __ATOMIC_RELAXED, __HIP_MEMORY_SCOPE_AGENT);
    q[4 * i + 3] = __hip_atomic_load(pb + 1, __ATOMIC_RELAXED, __HIP_MEMORY_SCOPE_AGENT);
  }
}

// ---- main: persistent, 2 decoupled waves per block, weights in regs ----
__global__ __launch_bounds__(128)
__attribute__((amdgpu_waves_per_eu(1, 1)))
void lstm_kernel(const short* __restrict__ xbf, const short* __restrict__ wswz,
                 uint32_t* __restrict__ hbuf32, uint32_t* __restrict__ hmir32,
                 uint32_t* __restrict__ tagbuf, uint32_t* __restrict__ flagbuf,
                 const float* __restrict__ dense_w, float* __restrict__ wpart) {
  __shared__ float lds_part[2][T_][16];   // 64 KB dense-head partials

  const int tid  = threadIdx.x;
  const int lane = tid & 63;
  const int wv   = tid >> 6;            // 0..1
  const int l15  = lane & 15;
  const int quad = lane >> 4;
  const int grp  = blockIdx.x & 15;     // same-XCD heuristic (fast path only)
  const int j    = blockIdx.x >> 4;     // 0..10
  const int tileg = 2 * j + wv;         // this wave's col tile 0..21

  // weights -> registers ONCE
  short8 wreg[4][KC];
  #pragma unroll
  for (int g = 0; g < 4; ++g)
    #pragma unroll
    for (int kc = 0; kc < KC; ++kc)
      wreg[g][kc] = *(const short8*)(wswz +
          (((size_t)kc * NT + (g * 22 + tileg)) * 64 + lane) * 8);

  const int col = tileg * 16 + l15;               // gate-relative col 0..351
  const float dwv = (col < U_) ? dense_w[col] : 0.f;
  float cst[4] = {0.f, 0.f, 0.f, 0.f};

  // producer store offset (R10 tag-in-word layout), +r*4 per row
  const int colrem = col & 31;
  const int fastoff = (((col >> 5) * 2 + ((colrem >> 2) & 1)) * 256)
                    + (((colrem >> 3) * 16 + quad * 4) * 4)
                    + (((colrem >> 1) & 1) * 2) + (col & 1);

  const short* xrow = xbf + ((size_t)(grp * NB + l15) * T_) * F_ + quad * 8;
  uint32_t* hb  = hbuf32 + (size_t)grp * 2 * SLOTW;
  uint32_t* hm  = hmir32 + (size_t)grp * 2 * SLOTW;
  uint32_t* tgg = tagbuf + (size_t)grp * 2 * 32;
  uint32_t* flagp = flagbuf + grp * 16;
  const int tagidx = (lane < 22) ? lane : 31;     // word31: always 0 -> pass

  bool mm = false;                                 // mirror (degraded) mode
  const short hs_init = (col == 350) ? (short)0x3F80 : 0;
  uint32_t wout[4], wout_prev[4];
  #pragma unroll
  for (int r = 0; r < 4; ++r)
    wout[r] = wout_prev[r] = ((uint32_t)(unsigned short)hs_init) << 16;
  float hn_prev[4] = {0.f, 0.f, 0.f, 0.f};

  #pragma unroll 1
  for (int t = 0; t < T_; ++t) {
    short8 axf = *(const short8*)(xrow + t * F_);

    // tag pre-gate probe issued early (hint only; data self-validates)
    const uint32_t want = (uint32_t)t;
    const uint32_t* tgr = tgg + (size_t)((t + 1) & 1) * 32;
    uint32_t tv = __hip_atomic_load(tgr + tagidx, __ATOMIC_RELAXED,
                                    __HIP_MEMORY_SCOPE_AGENT);

    // kc=0 (x-only) MFMA — h-independent; acc0 kept for verify-retry
    float4_ acc0[4];
    #pragma unroll
    for (int g = 0; g < 4; ++g) {
      float4_ z = (float4_){0.f, 0.f, 0.f, 0.f};
      acc0[g] = __builtin_amdgcn_mfma_f32_16x16x32_bf16(axf, wreg[g][0], z, 0, 0, 0);
    }

    // ---- pre-gate spin (fast mode only), with distress protocol ----
    if (!mm) {
      bool ready = (bool)__all((int)(lane >= 22 || tv == want));
      int tries = 0;
      while (!ready) {
        ++tries;
        if ((tries & 63) == 0) {
          uint32_t f = __hip_atomic_load(flagp, __ATOMIC_RELAXED,
                                         __HIP_MEMORY_SCOPE_SYSTEM);
          if (f) mm = true;
        }
        if (tries == 16384) {
          if (lane == 0)
            __hip_atomic_store(flagp, 1u, __ATOMIC_RELAXED,
                               __HIP_MEMORY_SCOPE_SYSTEM);
          mm = true;
        }
        if (mm) {
          uint32_t* md1 = hm + (size_t)((t + 1) & 1) * SLOTW + fastoff; // tag t
          uint32_t* md0 = hm + (size_t)(t & 1) * SLOTW + fastoff;       // tag t-1
          #pragma unroll
          for (int r = 0; r < 4; ++r) {
            __hip_atomic_store(md1 + r * 4, wout[r], __ATOMIC_RELAXED,
                               __HIP_MEMORY_SCOPE_AGENT);
            __hip_atomic_store(md0 + r * 4, wout_prev[r], __ATOMIC_RELAXED,
                               __HIP_MEMORY_SCOPE_AGENT);
          }
          break;
        }
        tv = __hip_atomic_load(tgr + tagidx, __ATOMIC_RELAXED,
                               __HIP_MEMORY_SCOPE_AGENT);
        ready = (bool)__all((int)(lane >= 22 || tv == want));
      }
    }

    // ---- issue data loads, then hide dense head (t-1) in the flight ----
    u64t q[44];
    {
      const u64t* dq = (const u64t*)((mm ? hm : hb)
                       + (size_t)((t + 1) & 1) * SLOTW) + (size_t)lane * 2;
      loadq44(q, dq);
    }
    if (t) {
      #pragma unroll
      for (int r = 0; r < 4; ++r) {
        float s = hn_prev[r];          // already * dwv
        s += __shfl_xor(s, 1); s += __shfl_xor(s, 2);
        s += __shfl_xor(s, 4); s += __shfl_xor(s, 8);
        if (l15 == 0) lds_part[wv][t - 1][quad * 4 + r] = s;
      }
    }

    // ---- speculative MFMA + concurrent 64-bit verify; retry on fail ----
    const u64t tp = (u64t)(want & 0xFFFFu) * 0x0000000100000001ull;
    float4_ acc[4];
    int vtries = 0;
    for (;;) {
      u64t bad = 0;
      #pragma unroll
      for (int i = 0; i < 11; ++i) {
        union { uint32_t w[4]; short8 s; } u;
        #pragma unroll
        for (int k = 0; k < 4; ++k) {
          uint32_t lo = (uint32_t)q[4 * i + k];
          uint32_t hi = (uint32_t)(q[4 * i + k] >> 32);
          u.w[k] = (lo >> 16) | (hi & 0xFFFF0000u);
          bad |= (q[4 * i + k] ^ tp);
        }
        #pragma unroll
        for (int g = 0; g < 4; ++g)
          acc[g] = __builtin_amdgcn_mfma_f32_16x16x32_bf16(
              u.s, wreg[g][i + 1], (i == 0) ? acc0[g] : acc[g], 0, 0, 0);
      }
      bad &= 0x0000FFFF0000FFFFull;
      if ((bool)__all((int)(bad == 0))) break;
      if (!mm && ++vtries >= 4096) {           // escalate: shouldn't happen
        if (lane == 0)
          __hip_atomic_store(flagp, 1u, __ATOMIC_RELAXED,
                             __HIP_MEMORY_SCOPE_SYSTEM);
        mm = true;
        uint32_t* md1 = hm + (size_t)((t + 1) & 1) * SLOTW + fastoff;
        uint32_t* md0 = hm + (size_t)(t & 1) * SLOTW + fastoff;
        #pragma unroll
        for (int r = 0; r < 4; ++r) {
          __hip_atomic_store(md1 + r * 4, wout[r], __ATOMIC_RELAXED,
                             __HIP_MEMORY_SCOPE_AGENT);
          __hip_atomic_store(md0 + r * 4, wout_prev[r], __ATOMIC_RELAXED,
                             __HIP_MEMORY_SCOPE_AGENT);
        }
      }
      const u64t* dq = (const u64t*)((mm ? hm : hb)
                       + (size_t)((t + 1) & 1) * SLOTW) + (size_t)lane * 2;
      loadq44(q, dq);
    }

    // ---- update: lane covers rows quad*4+r at its col ----
    uint32_t* hwr = hb + (size_t)(t & 1) * SLOTW;
    const uint32_t otag = (uint32_t)(t + 1);
    #pragma unroll
    for (int r = 0; r < 4; ++r) {
      float ig = __builtin_amdgcn_rcpf(1.f + __expf(-acc[0][r]));
      float fg = __builtin_amdgcn_rcpf(1.f + __expf(-acc[1][r]));
      float gg = fmaxf(acc[2][r], 0.f);
      float og = __builtin_amdgcn_rcpf(1.f + __expf(-acc[3][r]));
      float cn = fg * cst[r] + ig * gg;
      cst[r] = cn;
      float hnr = og * fmaxf(cn, 0.f);
      hn_prev[r] = hnr * dwv;                    // pre-scaled for dense head
      short hs = f2bf(hnr);
      if (col == 350) hs = (short)0x3F80;        // bias-row input stays 1.0
      else if (col == 351) hs = 0;
      wout_prev[r] = wout[r];
      wout[r] = (((uint32_t)(unsigned short)hs) << 16) | (otag & 0xFFFFu);
      // FAST: fire-and-forget workgroup store (L2-resident, no drain)
      __hip_atomic_store(hwr + fastoff + r * 4, wout[r],
                         __ATOMIC_RELAXED, __HIP_MEMORY_SCOPE_WORKGROUP);
    }
    // tag hint publish — RELAXED (no drain); data self-validates
    if (lane == 0)
      __hip_atomic_store(tgg + (size_t)(t & 1) * 32 + tileg, otag,
                         __ATOMIC_RELAXED, __HIP_MEMORY_SCOPE_WORKGROUP);
    // degraded mode: keep coherent mirror current
    if (mm) {
      uint32_t* hwrm = hm + (size_t)(t & 1) * SLOTW + fastoff;
      #pragma unroll
      for (int r = 0; r < 4; ++r)
        __hip_atomic_store(hwrm + r * 4, wout[r], __ATOMIC_RELAXED,
                           __HIP_MEMORY_SCOPE_AGENT);
    }
  }

  // final dense head (t = 511)
  #pragma unroll
  for (int r = 0; r < 4; ++r) {
    float s = hn_prev[r];
    s += __shfl_xor(s, 1); s += __shfl_xor(s, 2);
    s += __shfl_xor(s, 4); s += __shfl_xor(s, 8);
    if (l15 == 0) lds_part[wv][T_ - 1][quad * 4 + r] = s;
  }

  // bulk-store dense partials (once)
  __syncthreads();
  float* wp = wpart + ((size_t)(grp * NCB + j) * NB) * T_;
  for (int i = tid; i < NB * T_; i += 128) {
    int t = i & (T_ - 1), row = i >> 9;
    wp[(size_t)row * T_ + t] = lds_part[0][t][row] + lds_part[1][t][row];
  }
}

// ---- final: out[b,t] = db + sum_j wpart[grp][j][row][t] ----
__global__ void reduce_out(const float* __restrict__ wpart,
                           const float* __restrict__ dense_b,
                           float* __restrict__ out) {
  int i = blockIdx.x * 256 + threadIdx.x;   // i = b*T + t
  int b = i >> 9, t = i & 511;
  int grp = b >> 4, row = b & 15;
  float s = dense_b[0];
  #pragma unroll
  for (int j = 0; j < NCB; ++j)
    s += wpart[(((size_t)grp * NCB + j) * NB + row) * T_ + t];
  out[i] = s;
}

extern "C" void kernel_launch(void* const* d_in, const int* in_sizes, int n_in,
                              void* d_out, int out_size, void* d_ws, size_t ws_size,
                              hipStream_t stream) {
  const float* x    = (const float*)d_in[0];
  const float* kern = (const float*)d_in[1];
  const float* rk   = (const float*)d_in[2];
  const float* bias = (const float*)d_in[3];
  const float* dw   = (const float*)d_in[4];
  const float* db   = (const float*)d_in[5];
  float* out = (float*)d_out;

  char* ws = (char*)d_ws;
  short*    wswz   = (short*)(ws);
  short*    xbf    = (short*)(ws + OFF_XBF);
  uint32_t* hbuf32 = (uint32_t*)(ws + OFF_HBUF);
  uint32_t* hmir32 = (uint32_t*)(ws + OFF_HMIR);
  uint32_t* tagbuf = (uint32_t*)(ws + OFF_TAG);
  uint32_t* flagbuf= (uint32_t*)(ws + OFF_FLG);
  float*    wpart  = (float*)(ws + OFF_WP);

  prep_w<<<NT, 64, 0, stream>>>(kern, rk, bias, wswz);
  prep_x<<<(256 * T_ * F_) / (256 * 4), 256, 0, stream>>>(x, xbf);
  init_all<<<(NGRP * SLOTW) / 256, 256, 0, stream>>>(hbuf32, hmir32, tagbuf, flagbuf);
  lstm_kernel<<<NGRP * NCB, 128, 0, stream>>>(xbf, wswz, hbuf32, hmir32, tagbuf,
                                              flagbuf, dw, wpart);
  reduce_out<<<(256 * T_) / 256, 256, 0, stream>>>(wpart, db, out);
}

// Round 6
// 1222.204 us; speedup vs baseline: 1.1229x; 1.1229x over previous
//
#include <hip/hip_runtime.h>
#include <stdint.h>

// LSTM B=256,T=512,F=32,U=350; gates i,f,g(relu),o; h=o*relu(c); out=h.dw+db
//
// R13: R11 base (split tags + bf16 slab, proven 946us) + two latency cuts.
//  R12 postmortem: tag-in-word format doubled slab bytes + re-added
//  repack/verify VALU (absolute MFMA cycles unchanged -> verify never
//  re-ran; the format, not the protocol, caused the 946->1319 regression).
//  R13 changes vs R11 (protocol byte-identical):
//   - x software pipeline: FETCH 8.6MB == xbf size -> x streams from HBM;
//     R11 loaded axf at loop top and used it immediately in kc0 MFMA
//     (~500-900cy HBM/L2 stall on the step-serial path). Now axf for t+1
//     is prefetched right after the tag publish (~1.5kcy before use);
//     prologue loads t=0 once.
//   - dense head moved BETWEEN data stores and tag RELEASE publish: the
//     release's vmcnt(0) store-ack drain (~300cy) now overlaps the dense
//     head's VALU/shfl work instead of idling; publish time unchanged,
//     wave reaches its next poll ~300cy earlier.
//  Everything else verbatim R11: bf16 A-frag fast slab (11KB, no repack),
//  22-word tag array w/ RELEASE-workgroup publish, distress->mirror
//  degraded mode (R10 tag-in-word self-validating path), depth-2 ping-pong.

#define T_   512
#define F_   32
#define U_   350
#define G4   1400
#define NGRP 16
#define NB   16
#define NCB  11
#define KC   12
#define NT   88
#define HSLOTUS 5632    // ushorts per bf16 fast slot (11 blk * 512)
#define SLOTW   5632    // u32 words per mirror slot (R10 layout)

typedef __attribute__((ext_vector_type(8))) short  short8;
typedef __attribute__((ext_vector_type(4))) short  short4_;
typedef __attribute__((ext_vector_type(4))) float  float4_;
typedef unsigned long long u64t;

__device__ __forceinline__ short f2bf(float f) {
  union { float f; uint32_t u; } v; v.f = f;
  return (short)((v.u + 0x7FFFu + ((v.u >> 16) & 1u)) >> 16);
}

// ---- workspace layout (bytes) ----
#define SZ_W     (NT*KC*64*8*2u)                        // 1,081,344
#define OFF_XBF  (SZ_W)
#define SZ_XBF   (256u*T_*F_*2u)                        // 8,388,608
#define OFF_HBUF (OFF_XBF + SZ_XBF)
#define SZ_HBUF  (NGRP*2u*HSLOTUS*2u)                   // 360,448
#define OFF_HMIR (OFF_HBUF + SZ_HBUF)
#define SZ_HMIR  (NGRP*2u*SLOTW*4u)                     // 720,896
#define OFF_TAG  (OFF_HMIR + SZ_HMIR)
#define SZ_TAG   (NGRP*2u*32u*4u)                       // 4,096
#define OFF_FLG  (OFF_TAG + SZ_TAG)
#define SZ_FLG   (NGRP*16u*4u)                          // 1,024
#define OFF_WP   (OFF_FLG + SZ_FLG)
#define SZ_WP    (NGRP*NCB*NB*T_*4u)                    // 5,767,168

// ---- prep: W_swz[kc][tile][lane][8] bf16 in MFMA B-fragment order ----
__global__ void prep_w(const float* __restrict__ kern,
                       const float* __restrict__ rk,
                       const float* __restrict__ bias,
                       short* __restrict__ wswz) {
  const int tile = blockIdx.x, lane = threadIdx.x;
  const int g = tile / 22, jt = tile % 22;
  const int colg = jt * 16 + (lane & 15);
  const int src = g * U_ + colg;
  const bool valid = (colg < U_);
  const int kbase = (lane >> 4) * 8;
  for (int kc = 0; kc < KC; ++kc) {
    short8 pack;
    #pragma unroll
    for (int jj = 0; jj < 8; ++jj) {
      int k = kc * 32 + kbase + jj;
      float v = 0.f;
      if (valid) {
        if (k < F_)            v = kern[k * G4 + src];
        else if (k < F_ + U_)  v = rk[(k - F_) * G4 + src];
        else if (k == F_ + U_) v = bias[src];
      }
      pack[jj] = f2bf(v);
    }
    *(short8*)(wswz + (((size_t)kc * NT + tile) * 64 + lane) * 8) = pack;
  }
}

// ---- prep: x f32 -> bf16 ([b][t][f], contiguous 16B A-frag loads) ----
__global__ void prep_x(const float* __restrict__ x, short* __restrict__ xbf) {
  int i = (blockIdx.x * 256 + threadIdx.x) * 4;
  float4_ v = *(const float4_*)(x + i);
  short4_ o;
  #pragma unroll
  for (int jj = 0; jj < 4; ++jj) o[jj] = f2bf(v[jj]);
  *(short4_*)(xbf + i) = o;
}

// ---- init: slot1 = h_{-1}=0 tag 0 (bias col 350 = 1.0); tags; flag ----
// Fast slot0 / mirror slot0 need no init (reads are tag-gated / tag-in-word
// poison-safe). Tag slot0 init 0 is safe: slot0 wants odd tags only.
__global__ void init_all(unsigned short* __restrict__ hb16,
                         uint32_t* __restrict__ hmir32,
                         uint32_t* __restrict__ tagbuf,
                         uint32_t* __restrict__ flagbuf) {
  int i = blockIdx.x * 256 + threadIdx.x;            // 0 .. NGRP*5632-1
  int grp = i / HSLOTUS, rem = i % HSLOTUS;
  // fast bf16 slot1: rem = blk*512 + (quad_c*16+row)*8 + cpos
  {
    int blk = rem >> 9, quadc = (rem >> 7) & 3, cpos = rem & 7;
    int col = blk * 32 + quadc * 8 + cpos;
    hb16[(size_t)(grp * 2 + 1) * HSLOTUS + rem] =
        (col == 350) ? (unsigned short)0x3F80 : 0;
  }
  // mirror slot1 (R10 tag-in-word layout)
  {
    int blkm = rem >> 8, off = rem & 255;
    int fi = blkm >> 1, fk2 = blkm & 1, fquadc = off >> 6;
    int fk1 = (off >> 1) & 1, fb = off & 1;
    int fcol = fi * 32 + fquadc * 8 + fk2 * 4 + fk1 * 2 + fb;
    hmir32[(size_t)(grp * 2 + 1) * SLOTW + rem] =
        (fcol == 350) ? 0x3F800000u : 0u;
  }
  if (rem < 32) {
    tagbuf[(size_t)(grp * 2 + 0) * 32 + rem] = 0u;
    tagbuf[(size_t)(grp * 2 + 1) * 32 + rem] = 0u;
  }
  if (rem == 0) flagbuf[grp * 16] = 0u;
}

// ---- main: persistent, 2 decoupled waves per block, weights in regs ----
__global__ __launch_bounds__(128)
__attribute__((amdgpu_waves_per_eu(1, 1)))
void lstm_kernel(const short* __restrict__ xbf, const short* __restrict__ wswz,
                 unsigned short* __restrict__ hb16, uint32_t* __restrict__ hmir32,
                 uint32_t* __restrict__ tagbuf, uint32_t* __restrict__ flagbuf,
                 const float* __restrict__ dense_w, float* __restrict__ wpart) {
  __shared__ float lds_part[2][T_][16];   // 64 KB dense-head partials

  const int tid  = threadIdx.x;
  const int lane = tid & 63;
  const int wv   = tid >> 6;            // 0..1
  const int l15  = lane & 15;
  const int quad = lane >> 4;
  const int grp  = blockIdx.x & 15;     // same-XCD heuristic (fast path only)
  const int j    = blockIdx.x >> 4;     // 0..10
  const int tileg = 2 * j + wv;         // this wave's col tile 0..21

  // weights -> registers ONCE
  short8 wreg[4][KC];
  #pragma unroll
  for (int g = 0; g < 4; ++g)
    #pragma unroll
    for (int kc = 0; kc < KC; ++kc)
      wreg[g][kc] = *(const short8*)(wswz +
          (((size_t)kc * NT + (g * 22 + tileg)) * 64 + lane) * 8);

  const int col = tileg * 16 + l15;               // gate-relative col 0..351
  const float dwv = (col < U_) ? dense_w[col] : 0.f;
  float cst[4] = {0.f, 0.f, 0.f, 0.f};

  // fast bf16 producer: ushort idx = pbase_us + r*8 (rows quad*4+r)
  const int pblk = col >> 5, pc32 = col & 31;
  const int pbase_us = pblk * 512 + ((pc32 >> 3) * 16 + quad * 4) * 8 + (pc32 & 7);
  // mirror (R10 tag-in-word) offset, +r*4 per row
  const int colrem = col & 31;
  const int fastoff = (((col >> 5) * 2 + ((colrem >> 2) & 1)) * 256)
                    + (((colrem >> 3) * 16 + quad * 4) * 4)
                    + (((colrem >> 1) & 1) * 2) + (col & 1);

  const short* xrow = xbf + ((size_t)(grp * NB + l15) * T_) * F_ + quad * 8;
  unsigned short* hbb = hb16 + (size_t)grp * 2 * HSLOTUS;
  uint32_t* hm  = hmir32 + (size_t)grp * 2 * SLOTW;
  uint32_t* tgg = tagbuf + (size_t)grp * 2 * 32;
  uint32_t* flagp = flagbuf + grp * 16;
  const int tagidx = (lane < 22) ? lane : 31;     // word31: always 0

  bool mm = false;                                 // mirror (degraded) mode
  const short hs_init = (col == 350) ? (short)0x3F80 : 0;
  uint32_t wout[4], wout_prev[4];
  #pragma unroll
  for (int r = 0; r < 4; ++r)
    wout[r] = wout_prev[r] = ((uint32_t)(unsigned short)hs_init) << 16;

  // x software pipeline: prologue load for t=0 (one HBM stall, once)
  short8 axf = *(const short8*)(xrow);

  #pragma unroll 1
  for (int t = 0; t < T_; ++t) {
    // first tag probe issued BEFORE kc=0 MFMAs (latency overlap)
    const uint32_t want = (uint32_t)t;
    const uint32_t* tgr = tgg + (size_t)((t + 1) & 1) * 32;
    uint32_t tv = __hip_atomic_load(tgr + tagidx, __ATOMIC_RELAXED,
                                    __HIP_MEMORY_SCOPE_AGENT);

    // kc=0 (x-only) MFMA — h-independent; axf was prefetched last iter
    float4_ acc[4];
    #pragma unroll
    for (int g = 0; g < 4; ++g) {
      float4_ z = (float4_){0.f, 0.f, 0.f, 0.f};
      acc[g] = __builtin_amdgcn_mfma_f32_16x16x32_bf16(axf, wreg[g][0], z, 0, 0, 0);
    }

    short8 afr[11];
    bool ready = (bool)__all((int)(lane >= 22 || tv == want));
    bool gotm = false;
    int tries = 0;
    while (!ready) {
      ++tries;
      if (!mm) {
        if ((tries & 63) == 0) {                    // poll distress (system)
          uint32_t f = __hip_atomic_load(flagp, __ATOMIC_RELAXED,
                                         __HIP_MEMORY_SCOPE_SYSTEM);
          if (f) mm = true;
        }
        if (tries == 16384) {                       // raise distress
          if (lane == 0)
            __hip_atomic_store(flagp, 1u, __ATOMIC_RELAXED,
                               __HIP_MEMORY_SCOPE_SYSTEM);
          mm = true;
        }
        if (mm) {
          // dump last two h vectors (self-validating tag-in-word)
          uint32_t* md1 = hm + (size_t)((t + 1) & 1) * SLOTW + fastoff; // tag t
          uint32_t* md0 = hm + (size_t)(t & 1) * SLOTW + fastoff;      // tag t-1
          #pragma unroll
          for (int r = 0; r < 4; ++r) {
            __hip_atomic_store(md1 + r * 4, wout[r], __ATOMIC_RELAXED,
                               __HIP_MEMORY_SCOPE_AGENT);
            __hip_atomic_store(md0 + r * 4, wout_prev[r], __ATOMIC_RELAXED,
                               __HIP_MEMORY_SCOPE_AGENT);
          }
        }
      } else {
        // mirror attempt: R10's coalesced tag-in-word path
        const u64t* mq = (const u64t*)(hm + (size_t)((t + 1) & 1) * SLOTW)
                       + (size_t)lane * 2;
        u64t q[44];
        #pragma unroll
        for (int i = 0; i < 11; ++i) {
          const u64t* pa = mq + (size_t)(2 * i) * 128;
          const u64t* pb = mq + (size_t)(2 * i + 1) * 128;
          q[4 * i + 0] = __hip_atomic_load(pa,     __ATOMIC_RELAXED, __HIP_MEMORY_SCOPE_AGENT);
          q[4 * i + 1] = __hip_atomic_load(pa + 1, __ATOMIC_RELAXED, __HIP_MEMORY_SCOPE_AGENT);
          q[4 * i + 2] = __hip_atomic_load(pb,     __ATOMIC_RELAXED, __HIP_MEMORY_SCOPE_AGENT);
          q[4 * i + 3] = __hip_atomic_load(pb + 1, __ATOMIC_RELAXED, __HIP_MEMORY_SCOPE_AGENT);
        }
        const uint32_t tag16 = want & 0xFFFFu;
        uint32_t bad = 0;
        #pragma unroll
        for (int i = 0; i < 44; ++i) {
          bad |= ((uint32_t)q[i] ^ tag16);
          bad |= ((uint32_t)(q[i] >> 32) ^ tag16);
        }
        if ((bool)__all((int)((bad & 0xFFFFu) == 0))) {
          #pragma unroll
          for (int i = 0; i < 11; ++i) {
            union { uint32_t w[4]; short8 s; } u;
            #pragma unroll
            for (int k = 0; k < 4; ++k) {
              uint32_t lo = (uint32_t)q[4 * i + k];
              uint32_t hi = (uint32_t)(q[4 * i + k] >> 32);
              u.w[k] = (lo >> 16) | (hi & 0xFFFF0000u);
            }
            afr[i] = u.s;
          }
          gotm = true;
          break;
        }
      }
      tv = __hip_atomic_load(tgr + tagidx, __ATOMIC_RELAXED,
                             __HIP_MEMORY_SCOPE_AGENT);
      ready = (bool)__all((int)(lane >= 22 || tv == want));
    }

    if (!gotm) {
      // coalesced bf16 A-frag load: lane L reads 16B at blk*1024 + L*16
      const u64t* hq = (const u64t*)(hbb + (size_t)((t + 1) & 1) * HSLOTUS)
                     + (size_t)lane * 2;
      #pragma unroll
      for (int i = 0; i < 11; ++i) {
        union { u64t q[2]; short8 s; } u;
        u.q[0] = __hip_atomic_load(hq + (size_t)i * 128,     __ATOMIC_RELAXED, __HIP_MEMORY_SCOPE_AGENT);
        u.q[1] = __hip_atomic_load(hq + (size_t)i * 128 + 1, __ATOMIC_RELAXED, __HIP_MEMORY_SCOPE_AGENT);
        afr[i] = u.s;
      }
    }

    // MFMA over kc=1..11 (no repack needed)
    #pragma unroll
    for (int i = 0; i < 11; ++i)
      #pragma unroll
      for (int g = 0; g < 4; ++g)
        acc[g] = __builtin_amdgcn_mfma_f32_16x16x32_bf16(afr[i], wreg[g][i + 1], acc[g], 0, 0, 0);

    // update: lane covers rows quad*4+r at its col; gates in registers
    unsigned short* hwp = hbb + (size_t)(t & 1) * HSLOTUS + pbase_us;
    const uint32_t otag = (uint32_t)(t + 1);
    float hn[4];
    #pragma unroll
    for (int r = 0; r < 4; ++r) {
      float ig = __builtin_amdgcn_rcpf(1.f + __expf(-acc[0][r]));
      float fg = __builtin_amdgcn_rcpf(1.f + __expf(-acc[1][r]));
      float gg = fmaxf(acc[2][r], 0.f);
      float og = __builtin_amdgcn_rcpf(1.f + __expf(-acc[3][r]));
      float cn = fg * cst[r] + ig * gg;
      cst[r] = cn;
      hn[r] = og * fmaxf(cn, 0.f);
      short hs = f2bf(hn[r]);
      if (col == 350) hs = (short)0x3F80;        // bias-row input stays 1.0
      else if (col == 351) hs = 0;
      wout_prev[r] = wout[r];
      wout[r] = (((uint32_t)(unsigned short)hs) << 16) | (otag & 0xFFFFu);
      hwp[r * 8] = (unsigned short)hs;           // fast bf16 data store (L2)
    }

    // dense head BETWEEN stores and publish: store-ack drain overlaps this
    #pragma unroll
    for (int r = 0; r < 4; ++r) {
      float s = hn[r] * dwv;
      s += __shfl_xor(s, 1); s += __shfl_xor(s, 2);
      s += __shfl_xor(s, 4); s += __shfl_xor(s, 8);
      if (l15 == 0) lds_part[wv][t][quad * 4 + r] = s;
    }

    // publish tag with RELEASE (drains the 4 data stores — now mostly free)
    if (lane == 0)
      __hip_atomic_store(tgg + (size_t)(t & 1) * 32 + tileg, otag,
                         __ATOMIC_RELEASE, __HIP_MEMORY_SCOPE_WORKGROUP);
    // degraded mode: also keep the coherent mirror current
    if (mm) {
      uint32_t* hwrm = hm + (size_t)(t & 1) * SLOTW + fastoff;
      #pragma unroll
      for (int r = 0; r < 4; ++r)
        __hip_atomic_store(hwrm + r * 4, wout[r], __ATOMIC_RELAXED,
                           __HIP_MEMORY_SCOPE_AGENT);
    }

    // x prefetch for t+1 — ~1.5kcy ahead of its kc0 use, hides HBM latency
    if (t + 1 < T_) axf = *(const short8*)(xrow + (t + 1) * F_);
  }

  // bulk-store dense partials (once)
  __syncthreads();
  float* wp = wpart + ((size_t)(grp * NCB + j) * NB) * T_;
  for (int i = tid; i < NB * T_; i += 128) {
    int t = i & (T_ - 1), row = i >> 9;
    wp[(size_t)row * T_ + t] = lds_part[0][t][row] + lds_part[1][t][row];
  }
}

// ---- final: out[b,t] = db + sum_j wpart[grp][j][row][t] ----
__global__ void reduce_out(const float* __restrict__ wpart,
                           const float* __restrict__ dense_b,
                           float* __restrict__ out) {
  int i = blockIdx.x * 256 + threadIdx.x;   // i = b*T + t
  int b = i >> 9, t = i & 511;
  int grp = b >> 4, row = b & 15;
  float s = dense_b[0];
  #pragma unroll
  for (int j = 0; j < NCB; ++j)
    s += wpart[(((size_t)grp * NCB + j) * NB + row) * T_ + t];
  out[i] = s;
}

extern "C" void kernel_launch(void* const* d_in, const int* in_sizes, int n_in,
                              void* d_out, int out_size, void* d_ws, size_t ws_size,
                              hipStream_t stream) {
  const float* x    = (const float*)d_in[0];
  const float* kern = (const float*)d_in[1];
  const float* rk   = (const float*)d_in[2];
  const float* bias = (const float*)d_in[3];
  const float* dw   = (const float*)d_in[4];
  const float* db   = (const float*)d_in[5];
  float* out = (float*)d_out;

  char* ws = (char*)d_ws;
  short*          wswz   = (short*)(ws);
  short*          xbf    = (short*)(ws + OFF_XBF);
  unsigned short* hb16   = (unsigned short*)(ws + OFF_HBUF);
  uint32_t*       hmir32 = (uint32_t*)(ws + OFF_HMIR);
  uint32_t*       tagbuf = (uint32_t*)(ws + OFF_TAG);
  uint32_t*       flagbuf= (uint32_t*)(ws + OFF_FLG);
  float*          wpart  = (float*)(ws + OFF_WP);

  prep_w<<<NT, 64, 0, stream>>>(kern, rk, bias, wswz);
  prep_x<<<(256 * T_ * F_) / (256 * 4), 256, 0, stream>>>(x, xbf);
  init_all<<<(NGRP * HSLOTUS) / 256, 256, 0, stream>>>(hb16, hmir32, tagbuf, flagbuf);
  lstm_kernel<<<NGRP * NCB, 128, 0, stream>>>(xbf, wswz, hb16, hmir32, tagbuf,
                                              flagbuf, dw, wpart);
  reduce_out<<<(256 * T_) / 256, 256, 0, stream>>>(wpart, db, out);
}

// Round 7
// 929.438 us; speedup vs baseline: 1.4766x; 1.3150x over previous
//
#include <hip/hip_runtime.h>
#include <stdint.h>

// LSTM B=256,T=512,F=32,U=350; gates i,f,g(relu),o; h=o*relu(c); out=h.dw+db
//
// R14: R11 verbatim (946us: split tags + bf16 slab + publish-before-dense)
//  + a REAL x software pipeline.
//  R13 postmortem: (a) dense head moved before the RELEASE delayed every
//  publish (drain must cover its DS ops; consumers spun longer: absolute
//  VALU +60%) -> pre-publish work adds to the step recurrence, post-publish
//  work is free. (b) R13's x prefetch at loop BOTTOM had zero lead time
//  (used at next loop top).
//  R14 change (only one): issue x(t+1) load at the TOP of iteration t;
//  kc0 of t consumes the value loaded one full iteration (~4kcy) earlier.
//  This removes the serial ~500-900cy first-touch x stall (FETCH 8.6MB ==
//  one compulsory pass over xbf; all 22 waves ride the same line misses
//  BEFORE the tag spin, so the stall couldn't overlap producer wait).
//  Everything else byte-identical R11: bf16 A-frag fast slab (11KB, no
//  repack), 22-word tag array w/ RELEASE-workgroup publish, dense head
//  after publish, distress->mirror degraded mode, depth-2 ping-pong.

#define T_   512
#define F_   32
#define U_   350
#define G4   1400
#define NGRP 16
#define NB   16
#define NCB  11
#define KC   12
#define NT   88
#define HSLOTUS 5632    // ushorts per bf16 fast slot (11 blk * 512)
#define SLOTW   5632    // u32 words per mirror slot (R10 layout)

typedef __attribute__((ext_vector_type(8))) short  short8;
typedef __attribute__((ext_vector_type(4))) short  short4_;
typedef __attribute__((ext_vector_type(4))) float  float4_;
typedef unsigned long long u64t;

__device__ __forceinline__ short f2bf(float f) {
  union { float f; uint32_t u; } v; v.f = f;
  return (short)((v.u + 0x7FFFu + ((v.u >> 16) & 1u)) >> 16);
}

// ---- workspace layout (bytes) ----
#define SZ_W     (NT*KC*64*8*2u)                        // 1,081,344
#define OFF_XBF  (SZ_W)
#define SZ_XBF   (256u*T_*F_*2u)                        // 8,388,608
#define OFF_HBUF (OFF_XBF + SZ_XBF)
#define SZ_HBUF  (NGRP*2u*HSLOTUS*2u)                   // 360,448
#define OFF_HMIR (OFF_HBUF + SZ_HBUF)
#define SZ_HMIR  (NGRP*2u*SLOTW*4u)                     // 720,896
#define OFF_TAG  (OFF_HMIR + SZ_HMIR)
#define SZ_TAG   (NGRP*2u*32u*4u)                       // 4,096
#define OFF_FLG  (OFF_TAG + SZ_TAG)
#define SZ_FLG   (NGRP*16u*4u)                          // 1,024
#define OFF_WP   (OFF_FLG + SZ_FLG)
#define SZ_WP    (NGRP*NCB*NB*T_*4u)                    // 5,767,168

// ---- prep: W_swz[kc][tile][lane][8] bf16 in MFMA B-fragment order ----
__global__ void prep_w(const float* __restrict__ kern,
                       const float* __restrict__ rk,
                       const float* __restrict__ bias,
                       short* __restrict__ wswz) {
  const int tile = blockIdx.x, lane = threadIdx.x;
  const int g = tile / 22, jt = tile % 22;
  const int colg = jt * 16 + (lane & 15);
  const int src = g * U_ + colg;
  const bool valid = (colg < U_);
  const int kbase = (lane >> 4) * 8;
  for (int kc = 0; kc < KC; ++kc) {
    short8 pack;
    #pragma unroll
    for (int jj = 0; jj < 8; ++jj) {
      int k = kc * 32 + kbase + jj;
      float v = 0.f;
      if (valid) {
        if (k < F_)            v = kern[k * G4 + src];
        else if (k < F_ + U_)  v = rk[(k - F_) * G4 + src];
        else if (k == F_ + U_) v = bias[src];
      }
      pack[jj] = f2bf(v);
    }
    *(short8*)(wswz + (((size_t)kc * NT + tile) * 64 + lane) * 8) = pack;
  }
}

// ---- prep: x f32 -> bf16 ([b][t][f], contiguous 16B A-frag loads) ----
__global__ void prep_x(const float* __restrict__ x, short* __restrict__ xbf) {
  int i = (blockIdx.x * 256 + threadIdx.x) * 4;
  float4_ v = *(const float4_*)(x + i);
  short4_ o;
  #pragma unroll
  for (int jj = 0; jj < 4; ++jj) o[jj] = f2bf(v[jj]);
  *(short4_*)(xbf + i) = o;
}

// ---- init: slot1 = h_{-1}=0 tag 0 (bias col 350 = 1.0); tags; flag ----
// Fast slot0 / mirror slot0 need no init (reads are tag-gated / tag-in-word
// poison-safe). Tag slot0 init 0 is safe: slot0 wants odd tags only.
__global__ void init_all(unsigned short* __restrict__ hb16,
                         uint32_t* __restrict__ hmir32,
                         uint32_t* __restrict__ tagbuf,
                         uint32_t* __restrict__ flagbuf) {
  int i = blockIdx.x * 256 + threadIdx.x;            // 0 .. NGRP*5632-1
  int grp = i / HSLOTUS, rem = i % HSLOTUS;
  // fast bf16 slot1: rem = blk*512 + (quad_c*16+row)*8 + cpos
  {
    int blk = rem >> 9, quadc = (rem >> 7) & 3, cpos = rem & 7;
    int col = blk * 32 + quadc * 8 + cpos;
    hb16[(size_t)(grp * 2 + 1) * HSLOTUS + rem] =
        (col == 350) ? (unsigned short)0x3F80 : 0;
  }
  // mirror slot1 (R10 tag-in-word layout)
  {
    int blkm = rem >> 8, off = rem & 255;
    int fi = blkm >> 1, fk2 = blkm & 1, fquadc = off >> 6;
    int fk1 = (off >> 1) & 1, fb = off & 1;
    int fcol = fi * 32 + fquadc * 8 + fk2 * 4 + fk1 * 2 + fb;
    hmir32[(size_t)(grp * 2 + 1) * SLOTW + rem] =
        (fcol == 350) ? 0x3F800000u : 0u;
  }
  if (rem < 32) {
    tagbuf[(size_t)(grp * 2 + 0) * 32 + rem] = 0u;
    tagbuf[(size_t)(grp * 2 + 1) * 32 + rem] = 0u;
  }
  if (rem == 0) flagbuf[grp * 16] = 0u;
}

// ---- main: persistent, 2 decoupled waves per block, weights in regs ----
__global__ __launch_bounds__(128)
__attribute__((amdgpu_waves_per_eu(1, 1)))
void lstm_kernel(const short* __restrict__ xbf, const short* __restrict__ wswz,
                 unsigned short* __restrict__ hb16, uint32_t* __restrict__ hmir32,
                 uint32_t* __restrict__ tagbuf, uint32_t* __restrict__ flagbuf,
                 const float* __restrict__ dense_w, float* __restrict__ wpart) {
  __shared__ float lds_part[2][T_][16];   // 64 KB dense-head partials

  const int tid  = threadIdx.x;
  const int lane = tid & 63;
  const int wv   = tid >> 6;            // 0..1
  const int l15  = lane & 15;
  const int quad = lane >> 4;
  const int grp  = blockIdx.x & 15;     // same-XCD heuristic (fast path only)
  const int j    = blockIdx.x >> 4;     // 0..10
  const int tileg = 2 * j + wv;         // this wave's col tile 0..21

  // weights -> registers ONCE
  short8 wreg[4][KC];
  #pragma unroll
  for (int g = 0; g < 4; ++g)
    #pragma unroll
    for (int kc = 0; kc < KC; ++kc)
      wreg[g][kc] = *(const short8*)(wswz +
          (((size_t)kc * NT + (g * 22 + tileg)) * 64 + lane) * 8);

  const int col = tileg * 16 + l15;               // gate-relative col 0..351
  const float dwv = (col < U_) ? dense_w[col] : 0.f;
  float cst[4] = {0.f, 0.f, 0.f, 0.f};

  // fast bf16 producer: ushort idx = pbase_us + r*8 (rows quad*4+r)
  const int pblk = col >> 5, pc32 = col & 31;
  const int pbase_us = pblk * 512 + ((pc32 >> 3) * 16 + quad * 4) * 8 + (pc32 & 7);
  // mirror (R10 tag-in-word) offset, +r*4 per row
  const int colrem = col & 31;
  const int fastoff = (((col >> 5) * 2 + ((colrem >> 2) & 1)) * 256)
                    + (((colrem >> 3) * 16 + quad * 4) * 4)
                    + (((colrem >> 1) & 1) * 2) + (col & 1);

  const short* xrow = xbf + ((size_t)(grp * NB + l15) * T_) * F_ + quad * 8;
  unsigned short* hbb = hb16 + (size_t)grp * 2 * HSLOTUS;
  uint32_t* hm  = hmir32 + (size_t)grp * 2 * SLOTW;
  uint32_t* tgg = tagbuf + (size_t)grp * 2 * 32;
  uint32_t* flagp = flagbuf + grp * 16;
  const int tagidx = (lane < 22) ? lane : 31;     // word31: always 0

  bool mm = false;                                 // mirror (degraded) mode
  const short hs_init = (col == 350) ? (short)0x3F80 : 0;
  uint32_t wout[4], wout_prev[4];
  #pragma unroll
  for (int r = 0; r < 4; ++r)
    wout[r] = wout_prev[r] = ((uint32_t)(unsigned short)hs_init) << 16;

  // x software pipeline prologue: load t=0 (single cold stall, once)
  short8 axf = *(const short8*)(xrow);

  #pragma unroll 1
  for (int t = 0; t < T_; ++t) {
    // x prefetch for t+1 issued at the TOP of iter t: one full iteration
    // (~4kcy) of lead before its kc0 use. t=511 clamps to 0 (discarded).
    const int tn = (t + 1 < T_) ? (t + 1) : 0;
    short8 axf_nx = *(const short8*)(xrow + tn * F_);

    // first tag probe issued BEFORE kc=0 MFMAs (latency overlap)
    const uint32_t want = (uint32_t)t;
    const uint32_t* tgr = tgg + (size_t)((t + 1) & 1) * 32;
    uint32_t tv = __hip_atomic_load(tgr + tagidx, __ATOMIC_RELAXED,
                                    __HIP_MEMORY_SCOPE_AGENT);

    // kc=0 (x-only) MFMA — h-independent; axf loaded one iteration ago
    float4_ acc[4];
    #pragma unroll
    for (int g = 0; g < 4; ++g) {
      float4_ z = (float4_){0.f, 0.f, 0.f, 0.f};
      acc[g] = __builtin_amdgcn_mfma_f32_16x16x32_bf16(axf, wreg[g][0], z, 0, 0, 0);
    }

    short8 afr[11];
    bool ready = (bool)__all((int)(lane >= 22 || tv == want));
    bool gotm = false;
    int tries = 0;
    while (!ready) {
      ++tries;
      if (!mm) {
        if ((tries & 63) == 0) {                    // poll distress (system)
          uint32_t f = __hip_atomic_load(flagp, __ATOMIC_RELAXED,
                                         __HIP_MEMORY_SCOPE_SYSTEM);
          if (f) mm = true;
        }
        if (tries == 16384) {                       // raise distress
          if (lane == 0)
            __hip_atomic_store(flagp, 1u, __ATOMIC_RELAXED,
                               __HIP_MEMORY_SCOPE_SYSTEM);
          mm = true;
        }
        if (mm) {
          // dump last two h vectors (self-validating tag-in-word)
          uint32_t* md1 = hm + (size_t)((t + 1) & 1) * SLOTW + fastoff; // tag t
          uint32_t* md0 = hm + (size_t)(t & 1) * SLOTW + fastoff;      // tag t-1
          #pragma unroll
          for (int r = 0; r < 4; ++r) {
            __hip_atomic_store(md1 + r * 4, wout[r], __ATOMIC_RELAXED,
                               __HIP_MEMORY_SCOPE_AGENT);
            __hip_atomic_store(md0 + r * 4, wout_prev[r], __ATOMIC_RELAXED,
                               __HIP_MEMORY_SCOPE_AGENT);
          }
        }
      } else {
        // mirror attempt: R10's coalesced tag-in-word path
        const u64t* mq = (const u64t*)(hm + (size_t)((t + 1) & 1) * SLOTW)
                       + (size_t)lane * 2;
        u64t q[44];
        #pragma unroll
        for (int i = 0; i < 11; ++i) {
          const u64t* pa = mq + (size_t)(2 * i) * 128;
          const u64t* pb = mq + (size_t)(2 * i + 1) * 128;
          q[4 * i + 0] = __hip_atomic_load(pa,     __ATOMIC_RELAXED, __HIP_MEMORY_SCOPE_AGENT);
          q[4 * i + 1] = __hip_atomic_load(pa + 1, __ATOMIC_RELAXED, __HIP_MEMORY_SCOPE_AGENT);
          q[4 * i + 2] = __hip_atomic_load(pb,     __ATOMIC_RELAXED, __HIP_MEMORY_SCOPE_AGENT);
          q[4 * i + 3] = __hip_atomic_load(pb + 1, __ATOMIC_RELAXED, __HIP_MEMORY_SCOPE_AGENT);
        }
        const uint32_t tag16 = want & 0xFFFFu;
        uint32_t bad = 0;
        #pragma unroll
        for (int i = 0; i < 44; ++i) {
          bad |= ((uint32_t)q[i] ^ tag16);
          bad |= ((uint32_t)(q[i] >> 32) ^ tag16);
        }
        if ((bool)__all((int)((bad & 0xFFFFu) == 0))) {
          #pragma unroll
          for (int i = 0; i < 11; ++i) {
            union { uint32_t w[4]; short8 s; } u;
            #pragma unroll
            for (int k = 0; k < 4; ++k) {
              uint32_t lo = (uint32_t)q[4 * i + k];
              uint32_t hi = (uint32_t)(q[4 * i + k] >> 32);
              u.w[k] = (lo >> 16) | (hi & 0xFFFF0000u);
            }
            afr[i] = u.s;
          }
          gotm = true;
          break;
        }
      }
      tv = __hip_atomic_load(tgr + tagidx, __ATOMIC_RELAXED,
                             __HIP_MEMORY_SCOPE_AGENT);
      ready = (bool)__all((int)(lane >= 22 || tv == want));
    }

    if (!gotm) {
      // coalesced bf16 A-frag load: lane L reads 16B at blk*1024 + L*16
      const u64t* hq = (const u64t*)(hbb + (size_t)((t + 1) & 1) * HSLOTUS)
                     + (size_t)lane * 2;
      #pragma unroll
      for (int i = 0; i < 11; ++i) {
        union { u64t q[2]; short8 s; } u;
        u.q[0] = __hip_atomic_load(hq + (size_t)i * 128,     __ATOMIC_RELAXED, __HIP_MEMORY_SCOPE_AGENT);
        u.q[1] = __hip_atomic_load(hq + (size_t)i * 128 + 1, __ATOMIC_RELAXED, __HIP_MEMORY_SCOPE_AGENT);
        afr[i] = u.s;
      }
    }

    // MFMA over kc=1..11 (no repack needed)
    #pragma unroll
    for (int i = 0; i < 11; ++i)
      #pragma unroll
      for (int g = 0; g < 4; ++g)
        acc[g] = __builtin_amdgcn_mfma_f32_16x16x32_bf16(afr[i], wreg[g][i + 1], acc[g], 0, 0, 0);

    // update: lane covers rows quad*4+r at its col; gates in registers
    unsigned short* hwp = hbb + (size_t)(t & 1) * HSLOTUS + pbase_us;
    const uint32_t otag = (uint32_t)(t + 1);
    float hn[4];
    #pragma unroll
    for (int r = 0; r < 4; ++r) {
      float ig = __builtin_amdgcn_rcpf(1.f + __expf(-acc[0][r]));
      float fg = __builtin_amdgcn_rcpf(1.f + __expf(-acc[1][r]));
      float gg = fmaxf(acc[2][r], 0.f);
      float og = __builtin_amdgcn_rcpf(1.f + __expf(-acc[3][r]));
      float cn = fg * cst[r] + ig * gg;
      cst[r] = cn;
      hn[r] = og * fmaxf(cn, 0.f);
      short hs = f2bf(hn[r]);
      if (col == 350) hs = (short)0x3F80;        // bias-row input stays 1.0
      else if (col == 351) hs = 0;
      wout_prev[r] = wout[r];
      wout[r] = (((uint32_t)(unsigned short)hs) << 16) | (otag & 0xFFFFu);
      hwp[r * 8] = (unsigned short)hs;           // fast bf16 data store (L2)
    }
    // publish tag with RELEASE (drains the 4 data stores first)
    if (lane == 0)
      __hip_atomic_store(tgg + (size_t)(t & 1) * 32 + tileg, otag,
                         __ATOMIC_RELEASE, __HIP_MEMORY_SCOPE_WORKGROUP);
    // degraded mode: also keep the coherent mirror current
    if (mm) {
      uint32_t* hwrm = hm + (size_t)(t & 1) * SLOTW + fastoff;
      #pragma unroll
      for (int r = 0; r < 4; ++r)
        __hip_atomic_store(hwrm + r * 4, wout[r], __ATOMIC_RELAXED,
                           __HIP_MEMORY_SCOPE_AGENT);
    }

    // dense head AFTER publish (off the recurrence; wave has slack here)
    #pragma unroll
    for (int r = 0; r < 4; ++r) {
      float s = hn[r] * dwv;
      s += __shfl_xor(s, 1); s += __shfl_xor(s, 2);
      s += __shfl_xor(s, 4); s += __shfl_xor(s, 8);
      if (l15 == 0) lds_part[wv][t][quad * 4 + r] = s;
    }

    axf = axf_nx;                                  // pipeline shift
  }

  // bulk-store dense partials (once)
  __syncthreads();
  float* wp = wpart + ((size_t)(grp * NCB + j) * NB) * T_;
  for (int i = tid; i < NB * T_; i += 128) {
    int t = i & (T_ - 1), row = i >> 9;
    wp[(size_t)row * T_ + t] = lds_part[0][t][row] + lds_part[1][t][row];
  }
}

// ---- final: out[b,t] = db + sum_j wpart[grp][j][row][t] ----
__global__ void reduce_out(const float* __restrict__ wpart,
                           const float* __restrict__ dense_b,
                           float* __restrict__ out) {
  int i = blockIdx.x * 256 + threadIdx.x;   // i = b*T + t
  int b = i >> 9, t = i & 511;
  int grp = b >> 4, row = b & 15;
  float s = dense_b[0];
  #pragma unroll
  for (int j = 0; j < NCB; ++j)
    s += wpart[(((size_t)grp * NCB + j) * NB + row) * T_ + t];
  out[i] = s;
}

extern "C" void kernel_launch(void* const* d_in, const int* in_sizes, int n_in,
                              void* d_out, int out_size, void* d_ws, size_t ws_size,
                              hipStream_t stream) {
  const float* x    = (const float*)d_in[0];
  const float* kern = (const float*)d_in[1];
  const float* rk   = (const float*)d_in[2];
  const float* bias = (const float*)d_in[3];
  const float* dw   = (const float*)d_in[4];
  const float* db   = (const float*)d_in[5];
  float* out = (float*)d_out;

  char* ws = (char*)d_ws;
  short*          wswz   = (short*)(ws);
  short*          xbf    = (short*)(ws + OFF_XBF);
  unsigned short* hb16   = (unsigned short*)(ws + OFF_HBUF);
  uint32_t*       hmir32 = (uint32_t*)(ws + OFF_HMIR);
  uint32_t*       tagbuf = (uint32_t*)(ws + OFF_TAG);
  uint32_t*       flagbuf= (uint32_t*)(ws + OFF_FLG);
  float*          wpart  = (float*)(ws + OFF_WP);

  prep_w<<<NT, 64, 0, stream>>>(kern, rk, bias, wswz);
  prep_x<<<(256 * T_ * F_) / (256 * 4), 256, 0, stream>>>(x, xbf);
  init_all<<<(NGRP * HSLOTUS) / 256, 256, 0, stream>>>(hb16, hmir32, tagbuf, flagbuf);
  lstm_kernel<<<NGRP * NCB, 128, 0, stream>>>(xbf, wswz, hb16, hmir32, tagbuf,
                                              flagbuf, dw, wpart);
  reduce_out<<<(256 * T_) / 256, 256, 0, stream>>>(wpart, db, out);
}